// Round 1
// baseline (361.457 us; speedup 1.0000x reference)
//
#include <hip/hip_runtime.h>
#include <cstdint>

#define N_SAMPLES 16384
#define DIM 2048
#define PDIM 256
#define NB 32
#define NL 100
#define NSEG (NB * NL)

typedef float floatx4 __attribute__((ext_vector_type(4)));
typedef __bf16 bf16x8 __attribute__((ext_vector_type(8)));

__device__ __forceinline__ unsigned short f32_to_bf16(float f) {
    unsigned int u = __float_as_uint(f);
    u += 0x7fffu + ((u >> 16) & 1u);   // round-to-nearest-even
    return (unsigned short)(u >> 16);
}

// ---------------------------------------------------------------------------
// prep: convert weights to bf16, combine biases, build seg index
// ---------------------------------------------------------------------------
__global__ __launch_bounds__(256) void prep_kernel(
    const float* __restrict__ W1w, const float* __restrict__ W1b,
    const float* __restrict__ W2w, const float* __restrict__ W2b,
    const int* __restrict__ label, const int* __restrict__ lbatch,
    unsigned short* __restrict__ W1bf, unsigned short* __restrict__ W2bf,
    float* __restrict__ bias, int* __restrict__ seg)
{
    int i = blockIdx.x * 256 + threadIdx.x;   // grid covers PDIM*DIM exactly
    W1bf[i] = f32_to_bf16(W1w[i]);
    W2bf[i] = f32_to_bf16(W2w[i]);
    if (i < PDIM) bias[i] = W1b[i] + W2b[i];
    if (i < N_SAMPLES) seg[i] = lbatch[i] * NL + label[i];
}

// ---------------------------------------------------------------------------
// segmean: per (batch, 256-col chunk) WG. label_batch sorted -> contiguous
// row range via binary search. LDS per-label accumulators; thread t owns
// column t (bank = t%32, 2-way alias = free). Also emits x as bf16.
// ---------------------------------------------------------------------------
__global__ __launch_bounds__(256) void segmean_kernel(
    const float* __restrict__ x, const int* __restrict__ label,
    const int* __restrict__ lbatch,
    unsigned short* __restrict__ xb, unsigned short* __restrict__ Mb)
{
    __shared__ float acc[NL][256];   // 100 KB
    __shared__ int cnt[NL];
    const int tid = threadIdx.x;
    const int b = blockIdx.y;
    const int c0 = blockIdx.x * 256;

    for (int i = tid; i < NL * 256; i += 256) ((float*)acc)[i] = 0.f;
    if (tid < NL) cnt[tid] = 0;

    // lower_bound(b), lower_bound(b+1) over sorted label_batch
    int lo = 0, hi = N_SAMPLES;
    while (lo < hi) { int mid = (lo + hi) >> 1; if (lbatch[mid] < b) lo = mid + 1; else hi = mid; }
    const int r0 = lo;
    hi = N_SAMPLES;
    while (lo < hi) { int mid = (lo + hi) >> 1; if (lbatch[mid] < b + 1) lo = mid + 1; else hi = mid; }
    const int r1 = lo;

    __syncthreads();
    for (int r = r0 + tid; r < r1; r += 256) atomicAdd(&cnt[label[r]], 1);

    const float* xp = x + c0 + tid;
    unsigned short* xbp = xb + c0 + tid;
    #pragma unroll 4
    for (int r = r0; r < r1; ++r) {
        int l = label[r];                       // broadcast, cached
        float v = xp[(size_t)r * DIM];
        acc[l][tid] += v;                       // thread-private column: no race
        xbp[(size_t)r * DIM] = f32_to_bf16(v);
    }
    __syncthreads();

    float tot = 0.f;
    #pragma unroll
    for (int l = 0; l < NL; ++l) tot += acc[l][tid];
    const int cb = r1 - r0;
    for (int l = 0; l < NL; ++l) {
        int dc = cb - cnt[l];
        float m = (dc > 0) ? (tot - acc[l][tid]) / (float)dc : 0.f;
        Mb[(size_t)(b * NL + l) * DIM + c0 + tid] = f32_to_bf16(m);
    }
}

// ---------------------------------------------------------------------------
// GEMM: C[M,256] = A[M,K]_bf16 @ B[256,K]_bf16^T  (B rows = output cols)
// m97 structure: 2-barrier K-loop, global_load_lds width 16,
// mfma_f32_16x16x32_bf16. 4 waves in 2x2; wave subtile (BM/2)x(BN/2).
// A-frag: lane holds A[m=lane&15][k=(lane>>4)*8+j]; B-frag symmetric (B^T rows);
// D: row=(lane>>4)*4+reg, col=lane&15  (guide-verified layouts).
// FUSE epilogue: += bias[col] + add[seg[row]*256 + col]
// ---------------------------------------------------------------------------
template<int BM, int BN, bool FUSE>
__global__ __launch_bounds__(256) void gemm_bt_kernel(
    const unsigned short* __restrict__ A,
    const unsigned short* __restrict__ B,
    float* __restrict__ C,
    const float* __restrict__ bias,
    const float* __restrict__ add,
    const int* __restrict__ seg,
    int K)
{
    constexpr int HBM = BM / 2, HBN = BN / 2;
    constexpr int FM = BM / 32, FN = BN / 32;
    __shared__ __align__(16) unsigned short ldsA[BM * 32];
    __shared__ __align__(16) unsigned short ldsB[BN * 32];
    const int tid = threadIdx.x;
    const int lane = tid & 63;
    const int wave = tid >> 6;
    const int wr = wave >> 1, wc = wave & 1;
    const int quad = lane >> 4, l15 = lane & 15;
    const int m0 = blockIdx.x * BM;
    const int n0 = blockIdx.y * BN;
    const int srow = lane >> 2, schunk = lane & 3;   // staging: 16 rows x 4 chunks of 8 bf16

    floatx4 acc[FM][FN];
    #pragma unroll
    for (int i = 0; i < FM; ++i)
        #pragma unroll
        for (int j = 0; j < FN; ++j) acc[i][j] = (floatx4){0.f, 0.f, 0.f, 0.f};

    const unsigned short* Abase = A + (size_t)(m0 + srow) * K + schunk * 8;
    const unsigned short* Bbase = B + (size_t)(n0 + srow) * K + schunk * 8;

    for (int kk = 0; kk < K; kk += 32) {
        __syncthreads();
        #pragma unroll
        for (int ii = 0; ii < BM / 64; ++ii) {   // wave w stages 16-row chunk (ii*4+w)
            const int ch = ii * 4 + wave;
            __builtin_amdgcn_global_load_lds(
                (const __attribute__((address_space(1))) void*)(Abase + (size_t)ch * 16 * K + kk),
                (__attribute__((address_space(3))) void*)&ldsA[ch * 16 * 32], 16, 0, 0);
        }
        #pragma unroll
        for (int ii = 0; ii < BN / 64; ++ii) {
            const int ch = ii * 4 + wave;
            __builtin_amdgcn_global_load_lds(
                (const __attribute__((address_space(1))) void*)(Bbase + (size_t)ch * 16 * K + kk),
                (__attribute__((address_space(3))) void*)&ldsB[ch * 16 * 32], 16, 0, 0);
        }
        __syncthreads();

        bf16x8 af[FM], bfr[FN];
        #pragma unroll
        for (int mi = 0; mi < FM; ++mi)
            af[mi] = *(const bf16x8*)&ldsA[(wr * HBM + mi * 16 + l15) * 32 + quad * 8];
        #pragma unroll
        for (int ni = 0; ni < FN; ++ni)
            bfr[ni] = *(const bf16x8*)&ldsB[(wc * HBN + ni * 16 + l15) * 32 + quad * 8];
        #pragma unroll
        for (int mi = 0; mi < FM; ++mi)
            #pragma unroll
            for (int ni = 0; ni < FN; ++ni)
                acc[mi][ni] = __builtin_amdgcn_mfma_f32_16x16x32_bf16(
                    af[mi], bfr[ni], acc[mi][ni], 0, 0, 0);
    }

    #pragma unroll
    for (int mi = 0; mi < FM; ++mi) {
        const int rbase = m0 + wr * HBM + mi * 16 + quad * 4;
        #pragma unroll
        for (int ni = 0; ni < FN; ++ni) {
            const int col = n0 + wc * HBN + ni * 16 + l15;
            float bsum = 0.f;
            if constexpr (FUSE) bsum = bias[col];
            #pragma unroll
            for (int r = 0; r < 4; ++r) {
                const int row = rbase + r;
                float v = acc[mi][ni][r];
                if constexpr (FUSE) v += bsum + add[(size_t)seg[row] * PDIM + col];
                C[(size_t)row * PDIM + col] = v;
            }
        }
    }
}

// ---------------------------------------------------------------------------
extern "C" void kernel_launch(void* const* d_in, const int* in_sizes, int n_in,
                              void* d_out, int out_size, void* d_ws, size_t ws_size,
                              hipStream_t stream)
{
    const float* x      = (const float*)d_in[0];
    const int*   label  = (const int*)d_in[1];
    const int*   lbatch = (const int*)d_in[2];
    const float* W1w    = (const float*)d_in[3];
    const float* W1b    = (const float*)d_in[4];
    const float* W2w    = (const float*)d_in[5];
    const float* W2b    = (const float*)d_in[6];
    float* out = (float*)d_out;

    char* ws = (char*)d_ws;
    size_t off = 0;
    auto alloc = [&](size_t bytes) {
        void* p = ws + off;
        off = (off + bytes + 255) & ~(size_t)255;
        return p;
    };
    unsigned short* xb   = (unsigned short*)alloc((size_t)N_SAMPLES * DIM * 2); // 67 MB
    unsigned short* Mb   = (unsigned short*)alloc((size_t)NSEG * DIM * 2);      // 13 MB
    unsigned short* W1bf = (unsigned short*)alloc((size_t)PDIM * DIM * 2);      // 1 MB
    unsigned short* W2bf = (unsigned short*)alloc((size_t)PDIM * DIM * 2);      // 1 MB
    float* MW2  = (float*)alloc((size_t)NSEG * PDIM * 4);                       // 3.3 MB
    float* bias = (float*)alloc(PDIM * 4);
    int*   seg  = (int*)alloc(N_SAMPLES * 4);

    prep_kernel<<<PDIM * DIM / 256, 256, 0, stream>>>(
        W1w, W1b, W2w, W2b, label, lbatch, W1bf, W2bf, bias, seg);

    segmean_kernel<<<dim3(DIM / 256, NB), 256, 0, stream>>>(x, label, lbatch, xb, Mb);

    // MW2[3200,256] = M @ W2^T
    gemm_bt_kernel<64, 64, false><<<dim3(NSEG / 64, PDIM / 64), 256, 0, stream>>>(
        Mb, W2bf, MW2, nullptr, nullptr, nullptr, DIM);

    // out[16384,256] = x @ W1^T + bias + MW2[seg]
    gemm_bt_kernel<64, 128, true><<<dim3(N_SAMPLES / 64, PDIM / 128), 256, 0, stream>>>(
        xb, W1bf, out, bias, MW2, seg, DIM);
}